// Round 3
// baseline (971.334 us; speedup 1.0000x reference)
//
#include <hip/hip_runtime.h>
#include <hip/hip_bf16.h>

#define NFEAT 128
#define HID 16
#define NACT 18
#define NGRAPH 64
#define BSHIFT 7              // 128 nodes per bucket
#define BNODES 128
#define MAXBUCK 1024
#define CHUNK 8192            // edges per block in hist/scatter

__global__ __launch_bounds__(256) void k_init_deg(float* deg, int N) {
    int i = blockIdx.x * 256 + threadIdx.x;
    if (i < N) deg[i] = 1.0f;   // self-loop weight
}

// one pass over dst: bucket histogram (LDS-aggregated) + weighted degree (float atomics)
__global__ __launch_bounds__(256) void k_hist_deg(int* __restrict__ bcnt,
                                                  float* __restrict__ deg,
                                                  const int* __restrict__ dst,
                                                  const float* __restrict__ w,
                                                  int E, int nbuck) {
    __shared__ int hist[MAXBUCK];
    int t = threadIdx.x;
    for (int i = t; i < nbuck; i += 256) hist[i] = 0;
    __syncthreads();
    int beg = blockIdx.x * CHUNK;
    int end = min(beg + CHUNK, E);
    for (int e = beg + t; e < end; e += 256) {
        int d = dst[e];
        atomicAdd(&hist[d >> BSHIFT], 1);
        unsafeAtomicAdd(&deg[d], w[e]);
    }
    __syncthreads();
    for (int i = t; i < nbuck; i += 256) if (hist[i]) atomicAdd(&bcnt[i], hist[i]);
}

__global__ __launch_bounds__(1024) void k_scan(const int* __restrict__ bcnt,
                                               int* __restrict__ bptr,
                                               int* __restrict__ cursor,
                                               int nbuck, int E) {
    __shared__ int ts[1024];
    int t = threadIdx.x;
    int v = (t < nbuck) ? bcnt[t] : 0;
    ts[t] = v;
    __syncthreads();
    for (int off = 1; off < 1024; off <<= 1) {
        int tmp = (t >= off) ? ts[t - off] : 0;
        __syncthreads();
        ts[t] += tmp;
        __syncthreads();
    }
    if (t < nbuck) {
        int r = ts[t] - v;          // exclusive prefix
        bptr[t] = r;
        cursor[t] = r;
        if (t == nbuck - 1) bptr[nbuck] = E;
    }
}

__global__ __launch_bounds__(256) void k_dinv(float* deg, int N) {
    int i = blockIdx.x * 256 + threadIdx.x;
    if (i < N) {
        float d = deg[i];
        deg[i] = d > 0.f ? rsqrtf(d) : 0.f;
    }
}

// bucket-grouped scatter: record = (dstoff<<24 | src, norm)
__global__ __launch_bounds__(256) void k_bscatter(int2* __restrict__ edata,
                                                  int* __restrict__ cursor,
                                                  const int* __restrict__ src,
                                                  const int* __restrict__ dst,
                                                  const float* __restrict__ w,
                                                  const float* __restrict__ dinv,
                                                  int E, int nbuck) {
    __shared__ int cur[MAXBUCK];
    __shared__ int base[MAXBUCK];
    int t = threadIdx.x;
    for (int i = t; i < nbuck; i += 256) cur[i] = 0;
    __syncthreads();
    int beg = blockIdx.x * CHUNK;
    int end = min(beg + CHUNK, E);
    for (int e = beg + t; e < end; e += 256) atomicAdd(&cur[dst[e] >> BSHIFT], 1);
    __syncthreads();
    for (int i = t; i < nbuck; i += 256) {
        int c = cur[i];
        base[i] = c ? atomicAdd(&cursor[i], c) : 0;
        cur[i] = 0;
    }
    __syncthreads();
    for (int e = beg + t; e < end; e += 256) {
        int d = dst[e], s = src[e];
        int b = d >> BSHIFT;
        int off = atomicAdd(&cur[b], 1);
        float nrm = dinv[s] * w[e] * dinv[d];
        edata[base[b] + off] = make_int2(((d & (BNODES - 1)) << 24) | s, __float_as_int(nrm));
    }
}

// dense transform 1: h = x @ W1, 16 nodes per block
__global__ __launch_bounds__(256) void k_gemm1(const float* __restrict__ x,
                                               const float* __restrict__ W1,
                                               float* __restrict__ h) {
    __shared__ float xs[16 * 132];
    __shared__ float ws[NFEAT * HID];
    int t = threadIdx.x;
    for (int i = t; i < NFEAT * HID; i += 256) ws[i] = W1[i];
    const float* xblk = x + (size_t)blockIdx.x * 16 * NFEAT;
    #pragma unroll
    for (int rep = 0; rep < 2; rep++) {
        int i4 = (rep * 256 + t) * 4;
        int row = i4 >> 7, col = i4 & 127;
        float4 v = *reinterpret_cast<const float4*>(xblk + i4);
        *reinterpret_cast<float4*>(&xs[row * 132 + col]) = v;
    }
    __syncthreads();
    int r = t >> 4, j = t & 15;
    float acc = 0.f;
    #pragma unroll
    for (int k = 0; k < NFEAT; k++) acc += xs[r * 132 + k] * ws[k * HID + j];
    h[((size_t)blockIdx.x * 16 + r) * HID + j] = acc;
}

// bucketed SpMM into LDS tile + fused epilogue.
// LAYER 1: hout = relu(agg + dinv^2*hin + b) @ W2
// LAYER 2: pooled = segment-max over relu(agg + dinv^2*hin + b)
template <int LAYER>
__global__ __launch_bounds__(256) void k_spmm(const float* __restrict__ hin,
                                              const int2* __restrict__ edata,
                                              const int* __restrict__ bptr,
                                              const float* __restrict__ dinv,
                                              const float* __restrict__ bias,
                                              const float* __restrict__ W2,
                                              float* __restrict__ hout,
                                              const int* __restrict__ batch,
                                              unsigned* __restrict__ pooled,
                                              int N) {
    __shared__ float agg[BNODES * 17];
    __shared__ float w2s[16 * 16];
    __shared__ unsigned pool[NGRAPH * HID];
    int t = threadIdx.x;
    for (int i = t; i < BNODES * 17; i += 256) agg[i] = 0.f;
    if (LAYER == 1) w2s[t] = W2[t];
    if (LAYER == 2)
        for (int i = t; i < NGRAPH * HID; i += 256) pool[i] = 0u;
    __syncthreads();

    int b = blockIdx.x;
    int beg = bptr[b], end = bptr[b + 1];
    int j = t & 15;
    for (int p = beg + (t >> 4); p < end; p += 16) {
        int2 rec = edata[p];                        // same-addr across 16 lanes: broadcast
        int s = rec.x & 0xFFFFFF;
        int doff = ((unsigned)rec.x) >> 24;
        float v = __int_as_float(rec.y) * hin[s * HID + j];   // 64B line per edge
        atomicAdd(&agg[doff * 17 + j], v);          // ds_add_f32
    }
    __syncthreads();

    int nbase = b * BNODES;
    if (LAYER == 1) {
        #pragma unroll
        for (int it = 0; it < BNODES / 16; ++it) {
            int nl = (t >> 4) + it * 16;
            int n = nbase + nl;
            if (n < N) {
                float dv = dinv[n];
                float pre = agg[nl * 17 + j] + dv * dv * hin[(size_t)n * HID + j] + bias[j];
                agg[nl * 17 + j] = pre > 0.f ? pre : 0.f;
            }
        }
        __syncthreads();
        #pragma unroll
        for (int it = 0; it < BNODES / 16; ++it) {
            int nl = (t >> 4) + it * 16;
            int n = nbase + nl;
            if (n < N) {
                float o = 0.f;
                #pragma unroll
                for (int k = 0; k < 16; ++k) o += agg[nl * 17 + k] * w2s[k * 16 + j];
                hout[(size_t)n * HID + j] = o;
            }
        }
    } else {
        #pragma unroll
        for (int it = 0; it < BNODES / 16; ++it) {
            int nl = (t >> 4) + it * 16;
            int n = nbase + nl;
            if (n < N) {
                float dv = dinv[n];
                float v = agg[nl * 17 + j] + dv * dv * hin[(size_t)n * HID + j] + bias[j];
                v = v > 0.f ? v : 0.f;
                atomicMax(&pool[batch[n] * HID + j], __float_as_uint(v));
            }
        }
        __syncthreads();
        for (int i = t; i < NGRAPH * HID; i += 256) {
            unsigned u = pool[i];
            if (u) atomicMax(&pooled[i], u);
        }
    }
}

__global__ __launch_bounds__(256) void k_final(const unsigned* __restrict__ pooled,
                                               const float* __restrict__ Wl,
                                               const float* __restrict__ bl,
                                               float* __restrict__ out) {
    int gid = blockIdx.x * 256 + threadIdx.x;
    if (gid < NGRAPH * NACT) {
        int g = gid / NACT, a = gid - g * NACT;
        float acc = bl[a];
        #pragma unroll
        for (int k = 0; k < HID; k++)
            acc += __uint_as_float(pooled[g * HID + k]) * Wl[k * NACT + a];
        out[gid] = acc;
    }
}

extern "C" void kernel_launch(void* const* d_in, const int* in_sizes, int n_in,
                              void* d_out, int out_size, void* d_ws, size_t ws_size,
                              hipStream_t stream) {
    const float* x     = (const float*)d_in[0];
    const int*   ei    = (const int*)d_in[1];
    const float* ew    = (const float*)d_in[2];
    const int*   batch = (const int*)d_in[3];
    const float* W1    = (const float*)d_in[4];
    const float* b1    = (const float*)d_in[5];
    const float* W2    = (const float*)d_in[6];
    const float* b2    = (const float*)d_in[7];
    const float* Wl    = (const float*)d_in[8];
    const float* bl    = (const float*)d_in[9];
    float* out = (float*)d_out;

    int N = in_sizes[0] / NFEAT;
    int E = in_sizes[1] / 2;
    const int* srcIdx = ei;
    const int* dstIdx = ei + E;
    int nbuck = (N + BNODES - 1) >> BSHIFT;

    // workspace
    int2*  edata  = (int2*)d_ws;                        // [E]
    float* dinv   = (float*)(edata + E);                // [N] (deg -> dinv in place)
    float* h      = dinv + N;                           // [N*HID]
    float* h2     = h + (size_t)N * HID;                // [N*HID]
    int*   bcnt   = (int*)(h2 + (size_t)N * HID);       // [MAXBUCK]
    int*   bptr   = bcnt + MAXBUCK;                     // [MAXBUCK+1]
    int*   cursor = bptr + MAXBUCK + 1;                 // [MAXBUCK]
    unsigned* pooled = (unsigned*)(cursor + MAXBUCK);   // [NGRAPH*HID]

    int nbN = (N + 255) / 256;
    int nbC = (E + CHUNK - 1) / CHUNK;

    hipMemsetAsync(bcnt, 0, MAXBUCK * sizeof(int), stream);
    hipMemsetAsync(pooled, 0, NGRAPH * HID * sizeof(unsigned), stream);

    k_init_deg<<<nbN, 256, 0, stream>>>(dinv, N);
    k_hist_deg<<<nbC, 256, 0, stream>>>(bcnt, dinv, dstIdx, ew, E, nbuck);
    k_scan    <<<1, 1024, 0, stream>>>(bcnt, bptr, cursor, nbuck, E);
    k_dinv    <<<nbN, 256, 0, stream>>>(dinv, N);
    k_bscatter<<<nbC, 256, 0, stream>>>(edata, cursor, srcIdx, dstIdx, ew, dinv, E, nbuck);

    k_gemm1   <<<N / 16, 256, 0, stream>>>(x, W1, h);
    k_spmm<1> <<<nbuck, 256, 0, stream>>>(h, edata, bptr, dinv, b1, W2, h2, batch, pooled, N);
    k_spmm<2> <<<nbuck, 256, 0, stream>>>(h2, edata, bptr, dinv, b2, nullptr, nullptr, batch, pooled, N);
    k_final   <<<(NGRAPH * NACT + 255) / 256, 256, 0, stream>>>(pooled, Wl, bl, out);
}

// Round 4
// 436.190 us; speedup vs baseline: 2.2269x; 2.2269x over previous
//
#include <hip/hip_runtime.h>
#include <hip/hip_bf16.h>

#define NFEAT 128
#define HID 16
#define NACT 18
#define NGRAPH 64
#define BSHIFT 7              // 128 nodes per bucket
#define BNODES 128
#define MAXBUCK 1024
#define CHUNK 8192            // edges per block in hist/scatter
#define SORTCAP 5120          // max records per bucket (mean 4096, sigma 64: 16-sigma headroom)

__global__ __launch_bounds__(256) void k_init_deg(float* deg, int N) {
    int i = blockIdx.x * 256 + threadIdx.x;
    if (i < N) deg[i] = 1.0f;   // self-loop weight
}

// one pass over dst: bucket histogram (LDS-aggregated) + weighted degree (float atomics)
__global__ __launch_bounds__(256) void k_hist_deg(int* __restrict__ bcnt,
                                                  float* __restrict__ deg,
                                                  const int* __restrict__ dst,
                                                  const float* __restrict__ w,
                                                  int E, int nbuck) {
    __shared__ int hist[MAXBUCK];
    int t = threadIdx.x;
    for (int i = t; i < nbuck; i += 256) hist[i] = 0;
    __syncthreads();
    int beg = blockIdx.x * CHUNK;
    int end = min(beg + CHUNK, E);
    for (int e = beg + t; e < end; e += 256) {
        int d = dst[e];
        atomicAdd(&hist[d >> BSHIFT], 1);
        unsafeAtomicAdd(&deg[d], w[e]);
    }
    __syncthreads();
    for (int i = t; i < nbuck; i += 256) if (hist[i]) atomicAdd(&bcnt[i], hist[i]);
}

__global__ __launch_bounds__(1024) void k_scan(const int* __restrict__ bcnt,
                                               int* __restrict__ bptr,
                                               int* __restrict__ cursor,
                                               int* __restrict__ rowptr,
                                               int nbuck, int E, int N) {
    __shared__ int ts[1024];
    int t = threadIdx.x;
    int v = (t < nbuck) ? bcnt[t] : 0;
    ts[t] = v;
    __syncthreads();
    for (int off = 1; off < 1024; off <<= 1) {
        int tmp = (t >= off) ? ts[t - off] : 0;
        __syncthreads();
        ts[t] += tmp;
        __syncthreads();
    }
    if (t < nbuck) {
        int r = ts[t] - v;          // exclusive prefix
        bptr[t] = r;
        cursor[t] = r;
        if (t == nbuck - 1) bptr[nbuck] = E;
    }
    if (t == 0) rowptr[N] = E;
}

__global__ __launch_bounds__(256) void k_dinv(float* deg, int N) {
    int i = blockIdx.x * 256 + threadIdx.x;
    if (i < N) {
        float d = deg[i];
        deg[i] = d > 0.f ? rsqrtf(d) : 0.f;
    }
}

// bucket-grouped scatter: record = (dstoff<<24 | src, norm)
__global__ __launch_bounds__(256) void k_bscatter(int2* __restrict__ edata,
                                                  int* __restrict__ cursor,
                                                  const int* __restrict__ src,
                                                  const int* __restrict__ dst,
                                                  const float* __restrict__ w,
                                                  const float* __restrict__ dinv,
                                                  int E, int nbuck) {
    __shared__ int cur[MAXBUCK];
    __shared__ int base[MAXBUCK];
    int t = threadIdx.x;
    for (int i = t; i < nbuck; i += 256) cur[i] = 0;
    __syncthreads();
    int beg = blockIdx.x * CHUNK;
    int end = min(beg + CHUNK, E);
    for (int e = beg + t; e < end; e += 256) atomicAdd(&cur[dst[e] >> BSHIFT], 1);
    __syncthreads();
    for (int i = t; i < nbuck; i += 256) {
        int c = cur[i];
        base[i] = c ? atomicAdd(&cursor[i], c) : 0;
        cur[i] = 0;
    }
    __syncthreads();
    for (int e = beg + t; e < end; e += 256) {
        int d = dst[e], s = src[e];
        int b = d >> BSHIFT;
        int off = atomicAdd(&cur[b], 1);
        float nrm = dinv[s] * w[e] * dinv[d];
        edata[base[b] + off] = make_int2(((d & (BNODES - 1)) << 24) | s, __float_as_int(nrm));
    }
}

// per-bucket counting sort (in-place via LDS staging) + rowptr emission
__global__ __launch_bounds__(256) void k_bsort(int2* __restrict__ edata,
                                               const int* __restrict__ bptr,
                                               int* __restrict__ rowptr, int N) {
    __shared__ int2 stage[SORTCAP];
    __shared__ int hist[BNODES];
    __shared__ int cur[BNODES];
    __shared__ int ts[BNODES];
    int t = threadIdx.x;
    int b = blockIdx.x;
    int beg = bptr[b], end = bptr[b + 1];
    int cnt = end - beg;
    if (t < BNODES) hist[t] = 0;
    __syncthreads();
    for (int i = t; i < cnt; i += 256) {
        int2 r = edata[beg + i];
        stage[i] = r;
        atomicAdd(&hist[((unsigned)r.x) >> 24], 1);
    }
    __syncthreads();
    if (t < BNODES) ts[t] = hist[t];
    __syncthreads();
    for (int off = 1; off < BNODES; off <<= 1) {
        int v = (t < BNODES && t >= off) ? ts[t - off] : 0;
        __syncthreads();
        if (t < BNODES) ts[t] += v;
        __syncthreads();
    }
    if (t < BNODES) {
        int excl = ts[t] - hist[t];
        cur[t] = excl;
        int n = b * BNODES + t;
        if (n < N) rowptr[n] = beg + excl;
    }
    __syncthreads();
    for (int i = t; i < cnt; i += 256) {
        int2 r = stage[i];
        int pos = atomicAdd(&cur[((unsigned)r.x) >> 24], 1);
        edata[beg + pos] = r;   // random within 32KB window: L2-resident, lines fully dirtied
    }
}

// dense transform 1: h = x @ W1, 16 nodes per block
__global__ __launch_bounds__(256) void k_gemm1(const float* __restrict__ x,
                                               const float* __restrict__ W1,
                                               float* __restrict__ h) {
    __shared__ float xs[16 * 132];
    __shared__ float ws[NFEAT * HID];
    int t = threadIdx.x;
    for (int i = t; i < NFEAT * HID; i += 256) ws[i] = W1[i];
    const float* xblk = x + (size_t)blockIdx.x * 16 * NFEAT;
    #pragma unroll
    for (int rep = 0; rep < 2; rep++) {
        int i4 = (rep * 256 + t) * 4;
        int row = i4 >> 7, col = i4 & 127;
        float4 v = *reinterpret_cast<const float4*>(xblk + i4);
        *reinterpret_cast<float4*>(&xs[row * 132 + col]) = v;
    }
    __syncthreads();
    int r = t >> 4, j = t & 15;
    float acc = 0.f;
    #pragma unroll
    for (int k = 0; k < NFEAT; k++) acc += xs[r * 132 + k] * ws[k * HID + j];
    h[((size_t)blockIdx.x * 16 + r) * HID + j] = acc;
}

// per-node register-gather SpMM: 8 nodes/block, 32 lanes/node (2 edges in flight), no atomics.
// LAYER 1: hout = relu(agg + dinv^2*hin + b) @ W2
// LAYER 2: pooled = segment-max over relu(agg + dinv^2*hin + b)
template <int LAYER>
__global__ __launch_bounds__(256) void k_spmm(const float* __restrict__ hin,
                                              const int2* __restrict__ edata,
                                              const int* __restrict__ rowptr,
                                              const float* __restrict__ dinv,
                                              const float* __restrict__ bias,
                                              const float* __restrict__ W2,
                                              float* __restrict__ hout,
                                              const int* __restrict__ batch,
                                              unsigned* __restrict__ pooled,
                                              int N) {
    __shared__ float w2s[256];
    __shared__ float act[8][17];
    __shared__ unsigned pool[NGRAPH * HID];
    int t = threadIdx.x;
    if (LAYER == 1) w2s[t] = W2[t];
    if (LAYER == 2) {
        for (int i = t; i < NGRAPH * HID; i += 256) pool[i] = 0u;
        __syncthreads();
    }
    int r = t >> 5, hf = (t >> 4) & 1, j = t & 15;
    int n = blockIdx.x * 8 + r;
    float v = 0.f;
    if (n < N) {
        int beg = rowptr[n], end = rowptr[n + 1];
        float acc = 0.f;
        #pragma unroll 4
        for (int p = beg + hf; p < end; p += 2) {
            int2 rec = edata[p];                                    // 16-lane broadcast
            acc += __int_as_float(rec.y) * hin[(size_t)(rec.x & 0xFFFFFF) * HID + j];
        }
        acc += __shfl_xor(acc, 16, 32);                             // combine the two halves
        float dv = dinv[n];
        float pre = acc + dv * dv * hin[(size_t)n * HID + j] + bias[j];
        v = pre > 0.f ? pre : 0.f;
    }
    if (LAYER == 1) {
        if (hf == 0 && n < N) act[r][j] = v;
        __syncthreads();
        if (hf == 0 && n < N) {
            float o = 0.f;
            #pragma unroll
            for (int k = 0; k < HID; ++k) o += act[r][k] * w2s[k * 16 + j];
            hout[(size_t)n * HID + j] = o;
        }
    } else {
        if (hf == 0 && n < N)
            atomicMax(&pool[batch[n] * HID + j], __float_as_uint(v));
        __syncthreads();
        for (int i = t; i < NGRAPH * HID; i += 256) {
            unsigned u = pool[i];
            if (u) atomicMax(&pooled[i], u);
        }
    }
}

__global__ __launch_bounds__(256) void k_final(const unsigned* __restrict__ pooled,
                                               const float* __restrict__ Wl,
                                               const float* __restrict__ bl,
                                               float* __restrict__ out) {
    int gid = blockIdx.x * 256 + threadIdx.x;
    if (gid < NGRAPH * NACT) {
        int g = gid / NACT, a = gid - g * NACT;
        float acc = bl[a];
        #pragma unroll
        for (int k = 0; k < HID; k++)
            acc += __uint_as_float(pooled[g * HID + k]) * Wl[k * NACT + a];
        out[gid] = acc;
    }
}

extern "C" void kernel_launch(void* const* d_in, const int* in_sizes, int n_in,
                              void* d_out, int out_size, void* d_ws, size_t ws_size,
                              hipStream_t stream) {
    const float* x     = (const float*)d_in[0];
    const int*   ei    = (const int*)d_in[1];
    const float* ew    = (const float*)d_in[2];
    const int*   batch = (const int*)d_in[3];
    const float* W1    = (const float*)d_in[4];
    const float* b1    = (const float*)d_in[5];
    const float* W2    = (const float*)d_in[6];
    const float* b2    = (const float*)d_in[7];
    const float* Wl    = (const float*)d_in[8];
    const float* bl    = (const float*)d_in[9];
    float* out = (float*)d_out;

    int N = in_sizes[0] / NFEAT;
    int E = in_sizes[1] / 2;
    const int* srcIdx = ei;
    const int* dstIdx = ei + E;
    int nbuck = (N + BNODES - 1) >> BSHIFT;

    // workspace
    int2*  edata  = (int2*)d_ws;                        // [E]
    float* dinv   = (float*)(edata + E);                // [N] (deg -> dinv in place)
    float* h      = dinv + N;                           // [N*HID]
    float* h2     = h + (size_t)N * HID;                // [N*HID]
    int*   rowptr = (int*)(h2 + (size_t)N * HID);       // [N+1]
    int*   bcnt   = rowptr + N + 1;                     // [MAXBUCK]
    int*   bptr   = bcnt + MAXBUCK;                     // [MAXBUCK+1]
    int*   cursor = bptr + MAXBUCK + 1;                 // [MAXBUCK]
    unsigned* pooled = (unsigned*)(cursor + MAXBUCK);   // [NGRAPH*HID]

    int nbN = (N + 255) / 256;
    int nbC = (E + CHUNK - 1) / CHUNK;

    hipMemsetAsync(bcnt, 0, MAXBUCK * sizeof(int), stream);
    hipMemsetAsync(pooled, 0, NGRAPH * HID * sizeof(unsigned), stream);

    k_init_deg<<<nbN, 256, 0, stream>>>(dinv, N);
    k_hist_deg<<<nbC, 256, 0, stream>>>(bcnt, dinv, dstIdx, ew, E, nbuck);
    k_scan    <<<1, 1024, 0, stream>>>(bcnt, bptr, cursor, rowptr, nbuck, E, N);
    k_dinv    <<<nbN, 256, 0, stream>>>(dinv, N);
    k_bscatter<<<nbC, 256, 0, stream>>>(edata, cursor, srcIdx, dstIdx, ew, dinv, E, nbuck);
    k_bsort   <<<nbuck, 256, 0, stream>>>(edata, bptr, rowptr, N);

    k_gemm1   <<<N / 16, 256, 0, stream>>>(x, W1, h);
    k_spmm<1> <<<(N + 7) / 8, 256, 0, stream>>>(h, edata, rowptr, dinv, b1, W2, h2, batch, pooled, N);
    k_spmm<2> <<<(N + 7) / 8, 256, 0, stream>>>(h2, edata, rowptr, dinv, b2, nullptr, nullptr, batch, pooled, N);
    k_final   <<<(NGRAPH * NACT + 255) / 256, 256, 0, stream>>>(pooled, Wl, bl, out);
}

// Round 5
// 291.019 us; speedup vs baseline: 3.3377x; 1.4988x over previous
//
#include <hip/hip_runtime.h>
#include <hip/hip_bf16.h>

#define NFEAT 128
#define HID 16
#define NACT 18
#define NGRAPH 64
#define BSHIFT 7              // 128 nodes per bucket
#define BNODES 128
#define MAXBUCK 1024
#define CHUNK 8192            // edges per block in hist/scatter
#define SORTCAP 5120          // max records per bucket (mean 4096, sigma 64: 16-sigma headroom)

// bucket histogram only (LDS-aggregated int atomics; no global float atomics)
__global__ __launch_bounds__(256) void k_hist(int* __restrict__ bcnt,
                                              const int* __restrict__ dst,
                                              int E, int nbuck) {
    __shared__ int hist[MAXBUCK];
    int t = threadIdx.x;
    for (int i = t; i < nbuck; i += 256) hist[i] = 0;
    __syncthreads();
    int beg = blockIdx.x * CHUNK;
    int end = min(beg + CHUNK, E);
    for (int e = beg + t; e < end; e += 256) atomicAdd(&hist[dst[e] >> BSHIFT], 1);
    __syncthreads();
    for (int i = t; i < nbuck; i += 256) if (hist[i]) atomicAdd(&bcnt[i], hist[i]);
}

__global__ __launch_bounds__(1024) void k_scan(const int* __restrict__ bcnt,
                                               int* __restrict__ bptr,
                                               int* __restrict__ cursor,
                                               int* __restrict__ rowptr,
                                               int nbuck, int E, int N) {
    __shared__ int ts[1024];
    int t = threadIdx.x;
    int v = (t < nbuck) ? bcnt[t] : 0;
    ts[t] = v;
    __syncthreads();
    for (int off = 1; off < 1024; off <<= 1) {
        int tmp = (t >= off) ? ts[t - off] : 0;
        __syncthreads();
        ts[t] += tmp;
        __syncthreads();
    }
    if (t < nbuck) {
        int r = ts[t] - v;          // exclusive prefix
        bptr[t] = r;
        cursor[t] = r;
        if (t == nbuck - 1) bptr[nbuck] = E;
    }
    if (t == 0) rowptr[N] = E;
}

// bucket-grouped scatter: record = (dstoff<<24 | src, raw_w)
__global__ __launch_bounds__(256) void k_bscatter(int2* __restrict__ edata,
                                                  int* __restrict__ cursor,
                                                  const int* __restrict__ src,
                                                  const int* __restrict__ dst,
                                                  const float* __restrict__ w,
                                                  int E, int nbuck) {
    __shared__ int cur[MAXBUCK];
    __shared__ int base[MAXBUCK];
    int t = threadIdx.x;
    for (int i = t; i < nbuck; i += 256) cur[i] = 0;
    __syncthreads();
    int beg = blockIdx.x * CHUNK;
    int end = min(beg + CHUNK, E);
    for (int e = beg + t; e < end; e += 256) atomicAdd(&cur[dst[e] >> BSHIFT], 1);
    __syncthreads();
    for (int i = t; i < nbuck; i += 256) {
        int c = cur[i];
        base[i] = c ? atomicAdd(&cursor[i], c) : 0;
        cur[i] = 0;
    }
    __syncthreads();
    for (int e = beg + t; e < end; e += 256) {
        int d = dst[e], s = src[e];
        int b = d >> BSHIFT;
        int off = atomicAdd(&cur[b], 1);
        edata[base[b] + off] = make_int2(((d & (BNODES - 1)) << 24) | s, __float_as_int(w[e]));
    }
}

// per-bucket counting sort (LDS staging) + rowptr emission + weighted-degree -> dinv
__global__ __launch_bounds__(256) void k_bsort(int2* __restrict__ edata,
                                               const int* __restrict__ bptr,
                                               int* __restrict__ rowptr,
                                               float* __restrict__ dinv, int N) {
    __shared__ int2 stage[SORTCAP];
    __shared__ int hist[BNODES];
    __shared__ int cur[BNODES];
    __shared__ int ts[BNODES];
    __shared__ float wsum[BNODES];
    int t = threadIdx.x;
    int b = blockIdx.x;
    int beg = bptr[b], end = bptr[b + 1];
    int cnt = end - beg;
    if (t < BNODES) { hist[t] = 0; wsum[t] = 0.f; }
    __syncthreads();
    for (int i = t; i < cnt; i += 256) {
        int2 r = edata[beg + i];
        stage[i] = r;
        int doff = ((unsigned)r.x) >> 24;
        atomicAdd(&hist[doff], 1);
        atomicAdd(&wsum[doff], __int_as_float(r.y));
    }
    __syncthreads();
    if (t < BNODES) ts[t] = hist[t];
    __syncthreads();
    for (int off = 1; off < BNODES; off <<= 1) {
        int v = (t < BNODES && t >= off) ? ts[t - off] : 0;
        __syncthreads();
        if (t < BNODES) ts[t] += v;
        __syncthreads();
    }
    if (t < BNODES) {
        int excl = ts[t] - hist[t];
        cur[t] = excl;
        int n = b * BNODES + t;
        if (n < N) {
            rowptr[n] = beg + excl;
            dinv[n] = rsqrtf(1.0f + wsum[t]);   // self-loop weight 1 folded in
        }
    }
    __syncthreads();
    for (int i = t; i < cnt; i += 256) {
        int2 r = stage[i];
        int pos = atomicAdd(&cur[((unsigned)r.x) >> 24], 1);
        edata[beg + pos] = r;   // random within 32KB window: L2-resident
    }
}

// fold norm = dinv[src]*w*dinv[dst] into the sorted records
__global__ __launch_bounds__(256) void k_rescale(int2* __restrict__ edata,
                                                 const int* __restrict__ bptr,
                                                 const float* __restrict__ dinv, int N) {
    __shared__ float dvb[BNODES];
    int t = threadIdx.x;
    int b = blockIdx.x;
    int beg = bptr[b], end = bptr[b + 1];
    if (t < BNODES) {
        int n = b * BNODES + t;
        dvb[t] = (n < N) ? dinv[n] : 0.f;
    }
    __syncthreads();
    for (int i = beg + t; i < end; i += 256) {
        int2 r = edata[i];
        float nv = __int_as_float(r.y) * dinv[r.x & 0xFFFFFF] * dvb[((unsigned)r.x) >> 24];
        edata[i] = make_int2(r.x, __float_as_int(nv));
    }
}

// dense transform 1: h = x @ W1, 16 nodes per block
__global__ __launch_bounds__(256) void k_gemm1(const float* __restrict__ x,
                                               const float* __restrict__ W1,
                                               float* __restrict__ h) {
    __shared__ float xs[16 * 132];
    __shared__ float ws[NFEAT * HID];
    int t = threadIdx.x;
    for (int i = t; i < NFEAT * HID; i += 256) ws[i] = W1[i];
    const float* xblk = x + (size_t)blockIdx.x * 16 * NFEAT;
    #pragma unroll
    for (int rep = 0; rep < 2; rep++) {
        int i4 = (rep * 256 + t) * 4;
        int row = i4 >> 7, col = i4 & 127;
        float4 v = *reinterpret_cast<const float4*>(xblk + i4);
        *reinterpret_cast<float4*>(&xs[row * 132 + col]) = v;
    }
    __syncthreads();
    int r = t >> 4, j = t & 15;
    float acc = 0.f;
    #pragma unroll
    for (int k = 0; k < NFEAT; k++) acc += xs[r * 132 + k] * ws[k * HID + j];
    h[((size_t)blockIdx.x * 16 + r) * HID + j] = acc;
}

// per-node register-gather SpMM: 8 nodes/block, 32 lanes/node (2 edges in flight), no atomics.
// LAYER 1: hout = relu(agg + dinv^2*hin + b) @ W2
// LAYER 2: pooled = segment-max over relu(agg + dinv^2*hin + b)
template <int LAYER>
__global__ __launch_bounds__(256) void k_spmm(const float* __restrict__ hin,
                                              const int2* __restrict__ edata,
                                              const int* __restrict__ rowptr,
                                              const float* __restrict__ dinv,
                                              const float* __restrict__ bias,
                                              const float* __restrict__ W2,
                                              float* __restrict__ hout,
                                              const int* __restrict__ batch,
                                              unsigned* __restrict__ pooled,
                                              int N) {
    __shared__ float w2s[256];
    __shared__ float act[8][17];
    __shared__ unsigned pool[NGRAPH * HID];
    int t = threadIdx.x;
    if (LAYER == 1) w2s[t] = W2[t];
    if (LAYER == 2) {
        for (int i = t; i < NGRAPH * HID; i += 256) pool[i] = 0u;
        __syncthreads();
    }
    int r = t >> 5, hf = (t >> 4) & 1, j = t & 15;
    int n = blockIdx.x * 8 + r;
    float v = 0.f;
    if (n < N) {
        int beg = rowptr[n], end = rowptr[n + 1];
        float acc = 0.f;
        #pragma unroll 4
        for (int p = beg + hf; p < end; p += 2) {
            int2 rec = edata[p];                                    // 16-lane broadcast
            acc += __int_as_float(rec.y) * hin[(size_t)(rec.x & 0xFFFFFF) * HID + j];
        }
        acc += __shfl_xor(acc, 16, 32);                             // combine the two halves
        float dv = dinv[n];
        float pre = acc + dv * dv * hin[(size_t)n * HID + j] + bias[j];
        v = pre > 0.f ? pre : 0.f;
    }
    if (LAYER == 1) {
        if (hf == 0 && n < N) act[r][j] = v;
        __syncthreads();
        if (hf == 0 && n < N) {
            float o = 0.f;
            #pragma unroll
            for (int k = 0; k < HID; ++k) o += act[r][k] * w2s[k * 16 + j];
            hout[(size_t)n * HID + j] = o;
        }
    } else {
        if (hf == 0 && n < N)
            atomicMax(&pool[batch[n] * HID + j], __float_as_uint(v));
        __syncthreads();
        for (int i = t; i < NGRAPH * HID; i += 256) {
            unsigned u = pool[i];
            if (u) atomicMax(&pooled[i], u);
        }
    }
}

__global__ __launch_bounds__(256) void k_final(const unsigned* __restrict__ pooled,
                                               const float* __restrict__ Wl,
                                               const float* __restrict__ bl,
                                               float* __restrict__ out) {
    int gid = blockIdx.x * 256 + threadIdx.x;
    if (gid < NGRAPH * NACT) {
        int g = gid / NACT, a = gid - g * NACT;
        float acc = bl[a];
        #pragma unroll
        for (int k = 0; k < HID; k++)
            acc += __uint_as_float(pooled[g * HID + k]) * Wl[k * NACT + a];
        out[gid] = acc;
    }
}

extern "C" void kernel_launch(void* const* d_in, const int* in_sizes, int n_in,
                              void* d_out, int out_size, void* d_ws, size_t ws_size,
                              hipStream_t stream) {
    const float* x     = (const float*)d_in[0];
    const int*   ei    = (const int*)d_in[1];
    const float* ew    = (const float*)d_in[2];
    const int*   batch = (const int*)d_in[3];
    const float* W1    = (const float*)d_in[4];
    const float* b1    = (const float*)d_in[5];
    const float* W2    = (const float*)d_in[6];
    const float* b2    = (const float*)d_in[7];
    const float* Wl    = (const float*)d_in[8];
    const float* bl    = (const float*)d_in[9];
    float* out = (float*)d_out;

    int N = in_sizes[0] / NFEAT;
    int E = in_sizes[1] / 2;
    const int* srcIdx = ei;
    const int* dstIdx = ei + E;
    int nbuck = (N + BNODES - 1) >> BSHIFT;

    // workspace
    int2*  edata  = (int2*)d_ws;                        // [E]
    float* dinv   = (float*)(edata + E);                // [N]
    float* h      = dinv + N;                           // [N*HID]
    float* h2     = h + (size_t)N * HID;                // [N*HID]
    int*   rowptr = (int*)(h2 + (size_t)N * HID);       // [N+1]
    int*   bcnt   = rowptr + N + 1;                     // [MAXBUCK]
    int*   bptr   = bcnt + MAXBUCK;                     // [MAXBUCK+1]
    int*   cursor = bptr + MAXBUCK + 1;                 // [MAXBUCK]
    unsigned* pooled = (unsigned*)(cursor + MAXBUCK);   // [NGRAPH*HID]

    int nbC = (E + CHUNK - 1) / CHUNK;

    hipMemsetAsync(bcnt, 0, MAXBUCK * sizeof(int), stream);
    hipMemsetAsync(pooled, 0, NGRAPH * HID * sizeof(unsigned), stream);

    k_hist    <<<nbC, 256, 0, stream>>>(bcnt, dstIdx, E, nbuck);
    k_scan    <<<1, 1024, 0, stream>>>(bcnt, bptr, cursor, rowptr, nbuck, E, N);
    k_bscatter<<<nbC, 256, 0, stream>>>(edata, cursor, srcIdx, dstIdx, ew, E, nbuck);
    k_bsort   <<<nbuck, 256, 0, stream>>>(edata, bptr, rowptr, dinv, N);
    k_rescale <<<nbuck, 256, 0, stream>>>(edata, bptr, dinv, N);

    k_gemm1   <<<N / 16, 256, 0, stream>>>(x, W1, h);
    k_spmm<1> <<<(N + 7) / 8, 256, 0, stream>>>(h, edata, rowptr, dinv, b1, W2, h2, batch, pooled, N);
    k_spmm<2> <<<(N + 7) / 8, 256, 0, stream>>>(h2, edata, rowptr, dinv, b2, nullptr, nullptr, batch, pooled, N);
    k_final   <<<(NGRAPH * NACT + 255) / 256, 256, 0, stream>>>(pooled, Wl, bl, out);
}

// Round 6
// 273.190 us; speedup vs baseline: 3.5555x; 1.0653x over previous
//
#include <hip/hip_runtime.h>
#include <hip/hip_bf16.h>

#define NFEAT 128
#define HID 16
#define NACT 18
#define NGRAPH 64
#define BSHIFT 7              // 128 nodes per bucket
#define BNODES 128
#define MAXBUCK 1024
#define CHUNK 6144            // edges per block in hist/scatter (stage fits 2 blocks/CU)
#define SORTCAP 5120          // max records per bucket (mean 4096, sigma 64: 16-sigma headroom)

// bucket histogram only (LDS-aggregated int atomics)
__global__ __launch_bounds__(256) void k_hist(int* __restrict__ bcnt,
                                              const int* __restrict__ dst,
                                              int E, int nbuck) {
    __shared__ int hist[MAXBUCK];
    int t = threadIdx.x;
    for (int i = t; i < nbuck; i += 256) hist[i] = 0;
    __syncthreads();
    int beg = blockIdx.x * CHUNK;
    int end = min(beg + CHUNK, E);
    int cnt = end - beg;
    int nvec = cnt & ~3;
    for (int i = t * 4; i < nvec; i += 1024) {
        int4 d4 = *reinterpret_cast<const int4*>(dst + beg + i);
        atomicAdd(&hist[d4.x >> BSHIFT], 1);
        atomicAdd(&hist[d4.y >> BSHIFT], 1);
        atomicAdd(&hist[d4.z >> BSHIFT], 1);
        atomicAdd(&hist[d4.w >> BSHIFT], 1);
    }
    for (int i = nvec + t; i < cnt; i += 256) atomicAdd(&hist[dst[beg + i] >> BSHIFT], 1);
    __syncthreads();
    for (int i = t; i < nbuck; i += 256) if (hist[i]) atomicAdd(&bcnt[i], hist[i]);
}

__global__ __launch_bounds__(1024) void k_scan(const int* __restrict__ bcnt,
                                               int* __restrict__ bptr,
                                               int* __restrict__ cursor,
                                               int* __restrict__ rowptr,
                                               int nbuck, int E, int N) {
    __shared__ int ts[1024];
    int t = threadIdx.x;
    int v = (t < nbuck) ? bcnt[t] : 0;
    ts[t] = v;
    __syncthreads();
    for (int off = 1; off < 1024; off <<= 1) {
        int tmp = (t >= off) ? ts[t - off] : 0;
        __syncthreads();
        ts[t] += tmp;
        __syncthreads();
    }
    if (t < nbuck) {
        int r = ts[t] - v;          // exclusive prefix
        bptr[t] = r;
        cursor[t] = r;
        if (t == nbuck - 1) bptr[nbuck] = E;
    }
    if (t == 0) rowptr[N] = E;
}

// staged, write-coalesced bucket scatter: record = (dstoff<<24 | src, raw_w)
__global__ __launch_bounds__(256) void k_bscatter(int2* __restrict__ edata,
                                                  int* __restrict__ cursor,
                                                  const int* __restrict__ src,
                                                  const int* __restrict__ dst,
                                                  const float* __restrict__ w,
                                                  int E, int nbuck) {
    __shared__ int2 stage[CHUNK];              // 48KB
    __shared__ unsigned short bkid[CHUNK];     // 12KB
    __shared__ int hist[MAXBUCK];              // doubles as placement cursor
    __shared__ int pfx[MAXBUCK];
    __shared__ int basev[MAXBUCK];
    __shared__ int ts[256];
    int t = threadIdx.x;
    int beg = blockIdx.x * CHUNK;
    int end = min(beg + CHUNK, E);
    int cnt = end - beg;
    int nvec = cnt & ~3;
    for (int i = t; i < MAXBUCK; i += 256) hist[i] = 0;
    __syncthreads();
    // pass 1: local bucket histogram
    for (int i = t * 4; i < nvec; i += 1024) {
        int4 d4 = *reinterpret_cast<const int4*>(dst + beg + i);
        atomicAdd(&hist[d4.x >> BSHIFT], 1);
        atomicAdd(&hist[d4.y >> BSHIFT], 1);
        atomicAdd(&hist[d4.z >> BSHIFT], 1);
        atomicAdd(&hist[d4.w >> BSHIFT], 1);
    }
    for (int i = nvec + t; i < cnt; i += 256) atomicAdd(&hist[dst[beg + i] >> BSHIFT], 1);
    __syncthreads();
    // scan 1024 bins, 4 per thread
    int b4 = t * 4;
    int h0 = hist[b4], h1 = hist[b4 + 1], h2 = hist[b4 + 2], h3 = hist[b4 + 3];
    int s = h0 + h1 + h2 + h3;
    ts[t] = s;
    __syncthreads();
    for (int off = 1; off < 256; off <<= 1) {
        int tmp = (t >= off) ? ts[t - off] : 0;
        __syncthreads();
        ts[t] += tmp;
        __syncthreads();
    }
    int run = ts[t] - s;
    pfx[b4] = run; run += h0;
    pfx[b4 + 1] = run; run += h1;
    pfx[b4 + 2] = run; run += h2;
    pfx[b4 + 3] = run;
    __syncthreads();
    // reserve global runs; then hist becomes the placement cursor (= pfx copy)
    for (int b = t; b < nbuck; b += 256) {
        int c = hist[b];
        if (c) basev[b] = atomicAdd(&cursor[b], c);
    }
    __syncthreads();
    for (int b = t; b < MAXBUCK; b += 256) hist[b] = pfx[b];
    __syncthreads();
    // pass 2: place records bucket-sorted into LDS stage
    for (int i = t * 4; i < nvec; i += 1024) {
        int4 s4 = *reinterpret_cast<const int4*>(src + beg + i);
        int4 d4 = *reinterpret_cast<const int4*>(dst + beg + i);
        float4 w4 = *reinterpret_cast<const float4*>(w + beg + i);
        int bk, pos;
        bk = d4.x >> BSHIFT; pos = atomicAdd(&hist[bk], 1);
        stage[pos] = make_int2(((d4.x & (BNODES - 1)) << 24) | s4.x, __float_as_int(w4.x)); bkid[pos] = (unsigned short)bk;
        bk = d4.y >> BSHIFT; pos = atomicAdd(&hist[bk], 1);
        stage[pos] = make_int2(((d4.y & (BNODES - 1)) << 24) | s4.y, __float_as_int(w4.y)); bkid[pos] = (unsigned short)bk;
        bk = d4.z >> BSHIFT; pos = atomicAdd(&hist[bk], 1);
        stage[pos] = make_int2(((d4.z & (BNODES - 1)) << 24) | s4.z, __float_as_int(w4.z)); bkid[pos] = (unsigned short)bk;
        bk = d4.w >> BSHIFT; pos = atomicAdd(&hist[bk], 1);
        stage[pos] = make_int2(((d4.w & (BNODES - 1)) << 24) | s4.w, __float_as_int(w4.w)); bkid[pos] = (unsigned short)bk;
    }
    for (int i = nvec + t; i < cnt; i += 256) {
        int d = dst[beg + i], sv = src[beg + i];
        int bk = d >> BSHIFT;
        int pos = atomicAdd(&hist[bk], 1);
        stage[pos] = make_int2(((d & (BNODES - 1)) << 24) | sv, __float_as_int(w[beg + i]));
        bkid[pos] = (unsigned short)bk;
    }
    __syncthreads();
    // write-out: linear over stage -> coalesced runs at reserved global offsets
    for (int i = t; i < cnt; i += 256) {
        int bk = bkid[i];
        edata[basev[bk] + (i - pfx[bk])] = stage[i];
    }
}

// per-bucket counting sort (LDS staging) + rowptr emission + weighted-degree -> dinv
__global__ __launch_bounds__(256) void k_bsort(int2* __restrict__ edata,
                                               const int* __restrict__ bptr,
                                               int* __restrict__ rowptr,
                                               float* __restrict__ dinv, int N) {
    __shared__ int2 stage[SORTCAP];
    __shared__ int hist[BNODES];
    __shared__ int cur[BNODES];
    __shared__ int ts[BNODES];
    __shared__ float wsum[BNODES];
    int t = threadIdx.x;
    int b = blockIdx.x;
    int beg = bptr[b], end = bptr[b + 1];
    int cnt = end - beg;
    if (t < BNODES) { hist[t] = 0; wsum[t] = 0.f; }
    __syncthreads();
    for (int i = t; i < cnt; i += 256) {
        int2 r = edata[beg + i];
        stage[i] = r;
        int doff = ((unsigned)r.x) >> 24;
        atomicAdd(&hist[doff], 1);
        atomicAdd(&wsum[doff], __int_as_float(r.y));
    }
    __syncthreads();
    if (t < BNODES) ts[t] = hist[t];
    __syncthreads();
    for (int off = 1; off < BNODES; off <<= 1) {
        int v = (t < BNODES && t >= off) ? ts[t - off] : 0;
        __syncthreads();
        if (t < BNODES) ts[t] += v;
        __syncthreads();
    }
    if (t < BNODES) {
        int excl = ts[t] - hist[t];
        cur[t] = excl;
        int n = b * BNODES + t;
        if (n < N) {
            rowptr[n] = beg + excl;
            dinv[n] = rsqrtf(1.0f + wsum[t]);   // self-loop weight 1 folded in
        }
    }
    __syncthreads();
    for (int i = t; i < cnt; i += 256) {
        int2 r = stage[i];
        int pos = atomicAdd(&cur[((unsigned)r.x) >> 24], 1);
        edata[beg + pos] = r;   // random within 32KB window: L2-resident
    }
}

// dense transform 1: h = x @ W1, 16 nodes per block
__global__ __launch_bounds__(256) void k_gemm1(const float* __restrict__ x,
                                               const float* __restrict__ W1,
                                               float* __restrict__ h) {
    __shared__ float xs[16 * 132];
    __shared__ float ws[NFEAT * HID];
    int t = threadIdx.x;
    for (int i = t; i < NFEAT * HID; i += 256) ws[i] = W1[i];
    const float* xblk = x + (size_t)blockIdx.x * 16 * NFEAT;
    #pragma unroll
    for (int rep = 0; rep < 2; rep++) {
        int i4 = (rep * 256 + t) * 4;
        int row = i4 >> 7, col = i4 & 127;
        float4 v = *reinterpret_cast<const float4*>(xblk + i4);
        *reinterpret_cast<float4*>(&xs[row * 132 + col]) = v;
    }
    __syncthreads();
    int r = t >> 4, j = t & 15;
    float acc = 0.f;
    #pragma unroll
    for (int k = 0; k < NFEAT; k++) acc += xs[r * 132 + k] * ws[k * HID + j];
    h[((size_t)blockIdx.x * 16 + r) * HID + j] = acc;
}

// per-node register-gather SpMM with in-loop norm folding (records carry raw w):
//   acc = sum_e w_e*dinv[src_e]*hin[src_e][j];  pre = dv*(acc + dv*hin[n][j]) + b[j]
// LAYER 1: hout = relu(pre) @ W2   LAYER 2: pooled = segment-max over relu(pre)
template <int LAYER>
__global__ __launch_bounds__(256) void k_spmm(const float* __restrict__ hin,
                                              const int2* __restrict__ edata,
                                              const int* __restrict__ rowptr,
                                              const float* __restrict__ dinv,
                                              const float* __restrict__ bias,
                                              const float* __restrict__ W2,
                                              float* __restrict__ hout,
                                              const int* __restrict__ batch,
                                              unsigned* __restrict__ pooled,
                                              int N) {
    __shared__ float w2s[256];
    __shared__ float act[8][17];
    __shared__ unsigned pool[NGRAPH * HID];
    int t = threadIdx.x;
    if (LAYER == 1) w2s[t] = W2[t];
    if (LAYER == 2) {
        for (int i = t; i < NGRAPH * HID; i += 256) pool[i] = 0u;
        __syncthreads();
    }
    int r = t >> 5, hf = (t >> 4) & 1, j = t & 15;
    int n = blockIdx.x * 8 + r;
    float v = 0.f;
    if (n < N) {
        int beg = rowptr[n], end = rowptr[n + 1];
        float acc = 0.f;
        #pragma unroll 4
        for (int p = beg + hf; p < end; p += 2) {
            int2 rec = edata[p];                                    // 16-lane broadcast
            int s = rec.x & 0xFFFFFF;
            float wdvs = __int_as_float(rec.y) * dinv[s];           // L2-hot 4B broadcast
            acc += wdvs * hin[(size_t)s * HID + j];
        }
        acc += __shfl_xor(acc, 16, 32);                             // combine the two halves
        float dv = dinv[n];
        float pre = dv * (acc + dv * hin[(size_t)n * HID + j]) + bias[j];
        v = pre > 0.f ? pre : 0.f;
    }
    if (LAYER == 1) {
        if (hf == 0 && n < N) act[r][j] = v;
        __syncthreads();
        if (hf == 0 && n < N) {
            float o = 0.f;
            #pragma unroll
            for (int k = 0; k < HID; ++k) o += act[r][k] * w2s[k * 16 + j];
            hout[(size_t)n * HID + j] = o;
        }
    } else {
        if (hf == 0 && n < N)
            atomicMax(&pool[batch[n] * HID + j], __float_as_uint(v));
        __syncthreads();
        for (int i = t; i < NGRAPH * HID; i += 256) {
            unsigned u = pool[i];
            if (u) atomicMax(&pooled[i], u);
        }
    }
}

__global__ __launch_bounds__(256) void k_final(const unsigned* __restrict__ pooled,
                                               const float* __restrict__ Wl,
                                               const float* __restrict__ bl,
                                               float* __restrict__ out) {
    int gid = blockIdx.x * 256 + threadIdx.x;
    if (gid < NGRAPH * NACT) {
        int g = gid / NACT, a = gid - g * NACT;
        float acc = bl[a];
        #pragma unroll
        for (int k = 0; k < HID; k++)
            acc += __uint_as_float(pooled[g * HID + k]) * Wl[k * NACT + a];
        out[gid] = acc;
    }
}

extern "C" void kernel_launch(void* const* d_in, const int* in_sizes, int n_in,
                              void* d_out, int out_size, void* d_ws, size_t ws_size,
                              hipStream_t stream) {
    const float* x     = (const float*)d_in[0];
    const int*   ei    = (const int*)d_in[1];
    const float* ew    = (const float*)d_in[2];
    const int*   batch = (const int*)d_in[3];
    const float* W1    = (const float*)d_in[4];
    const float* b1    = (const float*)d_in[5];
    const float* W2    = (const float*)d_in[6];
    const float* b2    = (const float*)d_in[7];
    const float* Wl    = (const float*)d_in[8];
    const float* bl    = (const float*)d_in[9];
    float* out = (float*)d_out;

    int N = in_sizes[0] / NFEAT;
    int E = in_sizes[1] / 2;
    const int* srcIdx = ei;
    const int* dstIdx = ei + E;
    int nbuck = (N + BNODES - 1) >> BSHIFT;

    // workspace
    int2*  edata  = (int2*)d_ws;                        // [E]
    float* dinv   = (float*)(edata + E);                // [N]
    float* h      = dinv + N;                           // [N*HID]
    float* h2     = h + (size_t)N * HID;                // [N*HID]
    int*   rowptr = (int*)(h2 + (size_t)N * HID);       // [N+1]
    int*   bcnt   = rowptr + N + 1;                     // [MAXBUCK]
    int*   bptr   = bcnt + MAXBUCK;                     // [MAXBUCK+1]
    int*   cursor = bptr + MAXBUCK + 1;                 // [MAXBUCK]
    unsigned* pooled = (unsigned*)(cursor + MAXBUCK);   // [NGRAPH*HID]

    int nbC = (E + CHUNK - 1) / CHUNK;

    hipMemsetAsync(bcnt, 0, MAXBUCK * sizeof(int), stream);
    hipMemsetAsync(pooled, 0, NGRAPH * HID * sizeof(unsigned), stream);

    k_hist    <<<nbC, 256, 0, stream>>>(bcnt, dstIdx, E, nbuck);
    k_scan    <<<1, 1024, 0, stream>>>(bcnt, bptr, cursor, rowptr, nbuck, E, N);
    k_bscatter<<<nbC, 256, 0, stream>>>(edata, cursor, srcIdx, dstIdx, ew, E, nbuck);
    k_bsort   <<<nbuck, 256, 0, stream>>>(edata, bptr, rowptr, dinv, N);

    k_gemm1   <<<N / 16, 256, 0, stream>>>(x, W1, h);
    k_spmm<1> <<<(N + 7) / 8, 256, 0, stream>>>(h, edata, rowptr, dinv, b1, W2, h2, batch, pooled, N);
    k_spmm<2> <<<(N + 7) / 8, 256, 0, stream>>>(h2, edata, rowptr, dinv, b2, nullptr, nullptr, batch, pooled, N);
    k_final   <<<(NGRAPH * NACT + 255) / 256, 256, 0, stream>>>(pooled, Wl, bl, out);
}

// Round 7
// 272.492 us; speedup vs baseline: 3.5646x; 1.0026x over previous
//
#include <hip/hip_runtime.h>
#include <hip/hip_bf16.h>
#include <hip/hip_fp16.h>

#define NFEAT 128
#define HID 16
#define NACT 18
#define NGRAPH 64
#define BSHIFT 7              // 128 nodes per bucket
#define BNODES 128
#define MAXBUCK 1024
#define CHUNK 6144            // edges per block in hist/scatter (stage fits 2 blocks/CU)
#define SORTCAP 5120          // max records per bucket (mean 4096, sigma 64: 16-sigma headroom)

// bucket histogram only (LDS-aggregated int atomics)
__global__ __launch_bounds__(256) void k_hist(int* __restrict__ bcnt,
                                              const int* __restrict__ dst,
                                              int E, int nbuck) {
    __shared__ int hist[MAXBUCK];
    int t = threadIdx.x;
    for (int i = t; i < nbuck; i += 256) hist[i] = 0;
    __syncthreads();
    int beg = blockIdx.x * CHUNK;
    int end = min(beg + CHUNK, E);
    int cnt = end - beg;
    int nvec = cnt & ~3;
    for (int i = t * 4; i < nvec; i += 1024) {
        int4 d4 = *reinterpret_cast<const int4*>(dst + beg + i);
        atomicAdd(&hist[d4.x >> BSHIFT], 1);
        atomicAdd(&hist[d4.y >> BSHIFT], 1);
        atomicAdd(&hist[d4.z >> BSHIFT], 1);
        atomicAdd(&hist[d4.w >> BSHIFT], 1);
    }
    for (int i = nvec + t; i < cnt; i += 256) atomicAdd(&hist[dst[beg + i] >> BSHIFT], 1);
    __syncthreads();
    for (int i = t; i < nbuck; i += 256) if (hist[i]) atomicAdd(&bcnt[i], hist[i]);
}

__global__ __launch_bounds__(1024) void k_scan(const int* __restrict__ bcnt,
                                               int* __restrict__ bptr,
                                               int* __restrict__ cursor,
                                               int* __restrict__ rowptr,
                                               int nbuck, int E, int N) {
    __shared__ int ts[1024];
    int t = threadIdx.x;
    int v = (t < nbuck) ? bcnt[t] : 0;
    ts[t] = v;
    __syncthreads();
    for (int off = 1; off < 1024; off <<= 1) {
        int tmp = (t >= off) ? ts[t - off] : 0;
        __syncthreads();
        ts[t] += tmp;
        __syncthreads();
    }
    if (t < nbuck) {
        int r = ts[t] - v;          // exclusive prefix
        bptr[t] = r;
        cursor[t] = r;
        if (t == nbuck - 1) bptr[nbuck] = E;
    }
    if (t == 0) rowptr[N] = E;
}

// staged, write-coalesced bucket scatter: record = (dstoff<<24 | src, raw_w)
__global__ __launch_bounds__(256) void k_bscatter(int2* __restrict__ edata,
                                                  int* __restrict__ cursor,
                                                  const int* __restrict__ src,
                                                  const int* __restrict__ dst,
                                                  const float* __restrict__ w,
                                                  int E, int nbuck) {
    __shared__ int2 stage[CHUNK];              // 48KB
    __shared__ unsigned short bkid[CHUNK];     // 12KB
    __shared__ int hist[MAXBUCK];              // doubles as placement cursor
    __shared__ int pfx[MAXBUCK];
    __shared__ int basev[MAXBUCK];
    __shared__ int ts[256];
    int t = threadIdx.x;
    int beg = blockIdx.x * CHUNK;
    int end = min(beg + CHUNK, E);
    int cnt = end - beg;
    int nvec = cnt & ~3;
    for (int i = t; i < MAXBUCK; i += 256) hist[i] = 0;
    __syncthreads();
    // pass 1: local bucket histogram
    for (int i = t * 4; i < nvec; i += 1024) {
        int4 d4 = *reinterpret_cast<const int4*>(dst + beg + i);
        atomicAdd(&hist[d4.x >> BSHIFT], 1);
        atomicAdd(&hist[d4.y >> BSHIFT], 1);
        atomicAdd(&hist[d4.z >> BSHIFT], 1);
        atomicAdd(&hist[d4.w >> BSHIFT], 1);
    }
    for (int i = nvec + t; i < cnt; i += 256) atomicAdd(&hist[dst[beg + i] >> BSHIFT], 1);
    __syncthreads();
    // scan 1024 bins, 4 per thread
    int b4 = t * 4;
    int h0 = hist[b4], h1 = hist[b4 + 1], h2 = hist[b4 + 2], h3 = hist[b4 + 3];
    int s = h0 + h1 + h2 + h3;
    ts[t] = s;
    __syncthreads();
    for (int off = 1; off < 256; off <<= 1) {
        int tmp = (t >= off) ? ts[t - off] : 0;
        __syncthreads();
        ts[t] += tmp;
        __syncthreads();
    }
    int run = ts[t] - s;
    pfx[b4] = run; run += h0;
    pfx[b4 + 1] = run; run += h1;
    pfx[b4 + 2] = run; run += h2;
    pfx[b4 + 3] = run;
    __syncthreads();
    // reserve global runs; then hist becomes the placement cursor (= pfx copy)
    for (int b = t; b < nbuck; b += 256) {
        int c = hist[b];
        if (c) basev[b] = atomicAdd(&cursor[b], c);
    }
    __syncthreads();
    for (int b = t; b < MAXBUCK; b += 256) hist[b] = pfx[b];
    __syncthreads();
    // pass 2: place records bucket-sorted into LDS stage
    for (int i = t * 4; i < nvec; i += 1024) {
        int4 s4 = *reinterpret_cast<const int4*>(src + beg + i);
        int4 d4 = *reinterpret_cast<const int4*>(dst + beg + i);
        float4 w4 = *reinterpret_cast<const float4*>(w + beg + i);
        int bk, pos;
        bk = d4.x >> BSHIFT; pos = atomicAdd(&hist[bk], 1);
        stage[pos] = make_int2(((d4.x & (BNODES - 1)) << 24) | s4.x, __float_as_int(w4.x)); bkid[pos] = (unsigned short)bk;
        bk = d4.y >> BSHIFT; pos = atomicAdd(&hist[bk], 1);
        stage[pos] = make_int2(((d4.y & (BNODES - 1)) << 24) | s4.y, __float_as_int(w4.y)); bkid[pos] = (unsigned short)bk;
        bk = d4.z >> BSHIFT; pos = atomicAdd(&hist[bk], 1);
        stage[pos] = make_int2(((d4.z & (BNODES - 1)) << 24) | s4.z, __float_as_int(w4.z)); bkid[pos] = (unsigned short)bk;
        bk = d4.w >> BSHIFT; pos = atomicAdd(&hist[bk], 1);
        stage[pos] = make_int2(((d4.w & (BNODES - 1)) << 24) | s4.w, __float_as_int(w4.w)); bkid[pos] = (unsigned short)bk;
    }
    for (int i = nvec + t; i < cnt; i += 256) {
        int d = dst[beg + i], sv = src[beg + i];
        int bk = d >> BSHIFT;
        int pos = atomicAdd(&hist[bk], 1);
        stage[pos] = make_int2(((d & (BNODES - 1)) << 24) | sv, __float_as_int(w[beg + i]));
        bkid[pos] = (unsigned short)bk;
    }
    __syncthreads();
    // write-out: linear over stage -> coalesced runs at reserved global offsets
    for (int i = t; i < cnt; i += 256) {
        int bk = bkid[i];
        edata[basev[bk] + (i - pfx[bk])] = stage[i];
    }
}

// per-bucket counting sort (LDS staging) + rowptr emission + weighted-degree -> dinv
__global__ __launch_bounds__(256) void k_bsort(int2* __restrict__ edata,
                                               const int* __restrict__ bptr,
                                               int* __restrict__ rowptr,
                                               float* __restrict__ dinv, int N) {
    __shared__ int2 stage[SORTCAP];
    __shared__ int hist[BNODES];
    __shared__ int cur[BNODES];
    __shared__ int ts[BNODES];
    __shared__ float wsum[BNODES];
    int t = threadIdx.x;
    int b = blockIdx.x;
    int beg = bptr[b], end = bptr[b + 1];
    int cnt = end - beg;
    if (t < BNODES) { hist[t] = 0; wsum[t] = 0.f; }
    __syncthreads();
    for (int i = t; i < cnt; i += 256) {
        int2 r = edata[beg + i];
        stage[i] = r;
        int doff = ((unsigned)r.x) >> 24;
        atomicAdd(&hist[doff], 1);
        atomicAdd(&wsum[doff], __int_as_float(r.y));
    }
    __syncthreads();
    if (t < BNODES) ts[t] = hist[t];
    __syncthreads();
    for (int off = 1; off < BNODES; off <<= 1) {
        int v = (t < BNODES && t >= off) ? ts[t - off] : 0;
        __syncthreads();
        if (t < BNODES) ts[t] += v;
        __syncthreads();
    }
    if (t < BNODES) {
        int excl = ts[t] - hist[t];
        cur[t] = excl;
        int n = b * BNODES + t;
        if (n < N) {
            rowptr[n] = beg + excl;
            dinv[n] = rsqrtf(1.0f + wsum[t]);   // self-loop weight 1 folded in
        }
    }
    __syncthreads();
    for (int i = t; i < cnt; i += 256) {
        int2 r = stage[i];
        int pos = atomicAdd(&cur[((unsigned)r.x) >> 24], 1);
        edata[beg + pos] = r;   // random within 32KB window: L2-resident
    }
}

// dense transform 1: h = x @ W1 (fp16 output), 16 nodes per block
__global__ __launch_bounds__(256) void k_gemm1(const float* __restrict__ x,
                                               const float* __restrict__ W1,
                                               __half* __restrict__ h) {
    __shared__ float xs[16 * 132];
    __shared__ float ws[NFEAT * HID];
    int t = threadIdx.x;
    for (int i = t; i < NFEAT * HID; i += 256) ws[i] = W1[i];
    const float* xblk = x + (size_t)blockIdx.x * 16 * NFEAT;
    #pragma unroll
    for (int rep = 0; rep < 2; rep++) {
        int i4 = (rep * 256 + t) * 4;
        int row = i4 >> 7, col = i4 & 127;
        float4 v = *reinterpret_cast<const float4*>(xblk + i4);
        *reinterpret_cast<float4*>(&xs[row * 132 + col]) = v;
    }
    __syncthreads();
    int r = t >> 4, j = t & 15;
    float acc = 0.f;
    #pragma unroll
    for (int k = 0; k < NFEAT; k++) acc += xs[r * 132 + k] * ws[k * HID + j];
    h[((size_t)blockIdx.x * 16 + r) * HID + j] = __float2half(acc);
}

// per-node register-gather SpMM, fp16 features, 4 edges in flight per node.
// 8 nodes/block; per node: 32 lanes = 4 edge-slots x 8 j-pair lanes (half2).
//   acc = sum_e w_e*dinv[src_e]*hin[src_e][j];  pre = dv*(acc + dv*hin[n][j]) + b[j]
// LAYER 1: hout = relu(pre) @ W2 (fp16)   LAYER 2: pooled = segment-max relu(pre)
template <int LAYER>
__global__ __launch_bounds__(256) void k_spmm(const __half* __restrict__ hin,
                                              const int2* __restrict__ edata,
                                              const int* __restrict__ rowptr,
                                              const float* __restrict__ dinv,
                                              const float* __restrict__ bias,
                                              const float* __restrict__ W2,
                                              __half* __restrict__ hout,
                                              const int* __restrict__ batch,
                                              unsigned* __restrict__ pooled,
                                              int N) {
    __shared__ float w2s[256];
    __shared__ float act[8][18];
    __shared__ unsigned pool[NGRAPH * HID];
    int t = threadIdx.x;
    if (LAYER == 1) w2s[t] = W2[t];
    if (LAYER == 2) {
        for (int i = t; i < NGRAPH * HID; i += 256) pool[i] = 0u;
        __syncthreads();
    }
    int r = t >> 5;                 // node slot
    int sub = (t >> 3) & 3;         // edge slot
    int l8 = t & 7;                 // j-pair index
    int j0 = l8 * 2;
    int n = blockIdx.x * 8 + r;
    float a0 = 0.f, a1 = 0.f;
    if (n < N) {
        int beg = rowptr[n], end = rowptr[n + 1];
        for (int p = beg + sub; p < end; p += 4) {
            int2 rec = edata[p];                               // 8-lane broadcast
            int s = rec.x & 0xFFFFFF;
            float wd = __int_as_float(rec.y) * dinv[s];        // L2-hot broadcast
            __half2 hv = *reinterpret_cast<const __half2*>(hin + (size_t)s * HID + j0);
            float2 f = __half22float2(hv);
            a0 += wd * f.x;
            a1 += wd * f.y;
        }
    }
    a0 += __shfl_xor(a0, 8, 32);  a1 += __shfl_xor(a1, 8, 32);
    a0 += __shfl_xor(a0, 16, 32); a1 += __shfl_xor(a1, 16, 32);
    float v0 = 0.f, v1 = 0.f;
    if (n < N) {
        float dv = dinv[n];
        __half2 sv = *reinterpret_cast<const __half2*>(hin + (size_t)n * HID + j0);
        float2 sf = __half22float2(sv);
        v0 = dv * (a0 + dv * sf.x) + bias[j0];
        v1 = dv * (a1 + dv * sf.y) + bias[j0 + 1];
        v0 = v0 > 0.f ? v0 : 0.f;
        v1 = v1 > 0.f ? v1 : 0.f;
    }
    if (LAYER == 1) {
        if (sub == 0 && n < N) { act[r][j0] = v0; act[r][j0 + 1] = v1; }
        __syncthreads();
        int j = t & 15, hf = (t >> 4) & 1;
        if (hf == 0 && n < N) {
            float o = 0.f;
            #pragma unroll
            for (int k = 0; k < HID; ++k) o += act[r][k] * w2s[k * 16 + j];
            hout[(size_t)n * HID + j] = __float2half(o);
        }
    } else {
        if (sub == 0 && n < N) {
            int g = batch[n];
            atomicMax(&pool[g * HID + j0], __float_as_uint(v0));
            atomicMax(&pool[g * HID + j0 + 1], __float_as_uint(v1));
        }
        __syncthreads();
        for (int i = t; i < NGRAPH * HID; i += 256) {
            unsigned u = pool[i];
            if (u) atomicMax(&pooled[i], u);
        }
    }
}

__global__ __launch_bounds__(256) void k_final(const unsigned* __restrict__ pooled,
                                               const float* __restrict__ Wl,
                                               const float* __restrict__ bl,
                                               float* __restrict__ out) {
    int gid = blockIdx.x * 256 + threadIdx.x;
    if (gid < NGRAPH * NACT) {
        int g = gid / NACT, a = gid - g * NACT;
        float acc = bl[a];
        #pragma unroll
        for (int k = 0; k < HID; k++)
            acc += __uint_as_float(pooled[g * HID + k]) * Wl[k * NACT + a];
        out[gid] = acc;
    }
}

extern "C" void kernel_launch(void* const* d_in, const int* in_sizes, int n_in,
                              void* d_out, int out_size, void* d_ws, size_t ws_size,
                              hipStream_t stream) {
    const float* x     = (const float*)d_in[0];
    const int*   ei    = (const int*)d_in[1];
    const float* ew    = (const float*)d_in[2];
    const int*   batch = (const int*)d_in[3];
    const float* W1    = (const float*)d_in[4];
    const float* b1    = (const float*)d_in[5];
    const float* W2    = (const float*)d_in[6];
    const float* b2    = (const float*)d_in[7];
    const float* Wl    = (const float*)d_in[8];
    const float* bl    = (const float*)d_in[9];
    float* out = (float*)d_out;

    int N = in_sizes[0] / NFEAT;
    int E = in_sizes[1] / 2;
    const int* srcIdx = ei;
    const int* dstIdx = ei + E;
    int nbuck = (N + BNODES - 1) >> BSHIFT;

    // workspace
    int2*   edata  = (int2*)d_ws;                       // [E]
    float*  dinv   = (float*)(edata + E);               // [N]
    __half* h      = (__half*)(dinv + N);               // [N*HID] fp16
    __half* h2     = h + (size_t)N * HID;               // [N*HID] fp16
    int*    rowptr = (int*)(h2 + (size_t)N * HID);      // [N+1]
    int*    bcnt   = rowptr + N + 1;                    // [MAXBUCK]
    int*    bptr   = bcnt + MAXBUCK;                    // [MAXBUCK+1]
    int*    cursor = bptr + MAXBUCK + 1;                // [MAXBUCK]
    unsigned* pooled = (unsigned*)(cursor + MAXBUCK);   // [NGRAPH*HID]

    int nbC = (E + CHUNK - 1) / CHUNK;

    hipMemsetAsync(bcnt, 0, MAXBUCK * sizeof(int), stream);
    hipMemsetAsync(pooled, 0, NGRAPH * HID * sizeof(unsigned), stream);

    k_hist    <<<nbC, 256, 0, stream>>>(bcnt, dstIdx, E, nbuck);
    k_scan    <<<1, 1024, 0, stream>>>(bcnt, bptr, cursor, rowptr, nbuck, E, N);
    k_bscatter<<<nbC, 256, 0, stream>>>(edata, cursor, srcIdx, dstIdx, ew, E, nbuck);
    k_bsort   <<<nbuck, 256, 0, stream>>>(edata, bptr, rowptr, dinv, N);

    k_gemm1   <<<N / 16, 256, 0, stream>>>(x, W1, h);
    k_spmm<1> <<<(N + 7) / 8, 256, 0, stream>>>(h, edata, rowptr, dinv, b1, W2, h2, batch, pooled, N);
    k_spmm<2> <<<(N + 7) / 8, 256, 0, stream>>>(h2, edata, rowptr, dinv, b2, nullptr, nullptr, batch, pooled, N);
    k_final   <<<(NGRAPH * NACT + 255) / 256, 256, 0, stream>>>(pooled, Wl, bl, out);
}

// Round 8
// 240.889 us; speedup vs baseline: 4.0323x; 1.1312x over previous
//
#include <hip/hip_runtime.h>
#include <hip/hip_bf16.h>
#include <hip/hip_fp16.h>

#define NFEAT 128
#define HID 16
#define NACT 18
#define NGRAPH 64
#define BSHIFT 7              // 128 nodes per bucket
#define BNODES 128
#define MAXBUCK 1024
#define CHUNK 6144            // edges per block in hist/scatter (stage fits 2 blocks/CU)
#define SORTCAP 5120          // max records per bucket (mean 4096, sigma 64: 16-sigma headroom)

// bucket histogram only (LDS-aggregated int atomics)
__global__ __launch_bounds__(256) void k_hist(int* __restrict__ bcnt,
                                              const int* __restrict__ dst,
                                              int E, int nbuck) {
    __shared__ int hist[MAXBUCK];
    int t = threadIdx.x;
    for (int i = t; i < nbuck; i += 256) hist[i] = 0;
    __syncthreads();
    int beg = blockIdx.x * CHUNK;
    int end = min(beg + CHUNK, E);
    int cnt = end - beg;
    int nvec = cnt & ~3;
    for (int i = t * 4; i < nvec; i += 1024) {
        int4 d4 = *reinterpret_cast<const int4*>(dst + beg + i);
        atomicAdd(&hist[d4.x >> BSHIFT], 1);
        atomicAdd(&hist[d4.y >> BSHIFT], 1);
        atomicAdd(&hist[d4.z >> BSHIFT], 1);
        atomicAdd(&hist[d4.w >> BSHIFT], 1);
    }
    for (int i = nvec + t; i < cnt; i += 256) atomicAdd(&hist[dst[beg + i] >> BSHIFT], 1);
    __syncthreads();
    for (int i = t; i < nbuck; i += 256) if (hist[i]) atomicAdd(&bcnt[i], hist[i]);
}

__global__ __launch_bounds__(1024) void k_scan(const int* __restrict__ bcnt,
                                               int* __restrict__ bptr,
                                               int* __restrict__ cursor,
                                               int* __restrict__ rowptr,
                                               int nbuck, int E, int N) {
    __shared__ int ts[1024];
    int t = threadIdx.x;
    int v = (t < nbuck) ? bcnt[t] : 0;
    ts[t] = v;
    __syncthreads();
    for (int off = 1; off < 1024; off <<= 1) {
        int tmp = (t >= off) ? ts[t - off] : 0;
        __syncthreads();
        ts[t] += tmp;
        __syncthreads();
    }
    if (t < nbuck) {
        int r = ts[t] - v;          // exclusive prefix
        bptr[t] = r;
        cursor[t] = r;
        if (t == nbuck - 1) bptr[nbuck] = E;
    }
    if (t == 0) rowptr[N] = E;
}

// staged, write-coalesced bucket scatter: record = (dstoff<<24 | src, raw_w)
__global__ __launch_bounds__(256) void k_bscatter(int2* __restrict__ edata,
                                                  int* __restrict__ cursor,
                                                  const int* __restrict__ src,
                                                  const int* __restrict__ dst,
                                                  const float* __restrict__ w,
                                                  int E, int nbuck) {
    __shared__ int2 stage[CHUNK];              // 48KB
    __shared__ unsigned short bkid[CHUNK];     // 12KB
    __shared__ int hist[MAXBUCK];              // doubles as placement cursor
    __shared__ int pfx[MAXBUCK];
    __shared__ int basev[MAXBUCK];
    __shared__ int ts[256];
    int t = threadIdx.x;
    int beg = blockIdx.x * CHUNK;
    int end = min(beg + CHUNK, E);
    int cnt = end - beg;
    int nvec = cnt & ~3;
    for (int i = t; i < MAXBUCK; i += 256) hist[i] = 0;
    __syncthreads();
    // pass 1: local bucket histogram
    for (int i = t * 4; i < nvec; i += 1024) {
        int4 d4 = *reinterpret_cast<const int4*>(dst + beg + i);
        atomicAdd(&hist[d4.x >> BSHIFT], 1);
        atomicAdd(&hist[d4.y >> BSHIFT], 1);
        atomicAdd(&hist[d4.z >> BSHIFT], 1);
        atomicAdd(&hist[d4.w >> BSHIFT], 1);
    }
    for (int i = nvec + t; i < cnt; i += 256) atomicAdd(&hist[dst[beg + i] >> BSHIFT], 1);
    __syncthreads();
    // scan 1024 bins, 4 per thread
    int b4 = t * 4;
    int h0 = hist[b4], h1 = hist[b4 + 1], h2 = hist[b4 + 2], h3 = hist[b4 + 3];
    int s = h0 + h1 + h2 + h3;
    ts[t] = s;
    __syncthreads();
    for (int off = 1; off < 256; off <<= 1) {
        int tmp = (t >= off) ? ts[t - off] : 0;
        __syncthreads();
        ts[t] += tmp;
        __syncthreads();
    }
    int run = ts[t] - s;
    pfx[b4] = run; run += h0;
    pfx[b4 + 1] = run; run += h1;
    pfx[b4 + 2] = run; run += h2;
    pfx[b4 + 3] = run;
    __syncthreads();
    // reserve global runs; then hist becomes the placement cursor (= pfx copy)
    for (int b = t; b < nbuck; b += 256) {
        int c = hist[b];
        if (c) basev[b] = atomicAdd(&cursor[b], c);
    }
    __syncthreads();
    for (int b = t; b < MAXBUCK; b += 256) hist[b] = pfx[b];
    __syncthreads();
    // pass 2: place records bucket-sorted into LDS stage
    for (int i = t * 4; i < nvec; i += 1024) {
        int4 s4 = *reinterpret_cast<const int4*>(src + beg + i);
        int4 d4 = *reinterpret_cast<const int4*>(dst + beg + i);
        float4 w4 = *reinterpret_cast<const float4*>(w + beg + i);
        int bk, pos;
        bk = d4.x >> BSHIFT; pos = atomicAdd(&hist[bk], 1);
        stage[pos] = make_int2(((d4.x & (BNODES - 1)) << 24) | s4.x, __float_as_int(w4.x)); bkid[pos] = (unsigned short)bk;
        bk = d4.y >> BSHIFT; pos = atomicAdd(&hist[bk], 1);
        stage[pos] = make_int2(((d4.y & (BNODES - 1)) << 24) | s4.y, __float_as_int(w4.y)); bkid[pos] = (unsigned short)bk;
        bk = d4.z >> BSHIFT; pos = atomicAdd(&hist[bk], 1);
        stage[pos] = make_int2(((d4.z & (BNODES - 1)) << 24) | s4.z, __float_as_int(w4.z)); bkid[pos] = (unsigned short)bk;
        bk = d4.w >> BSHIFT; pos = atomicAdd(&hist[bk], 1);
        stage[pos] = make_int2(((d4.w & (BNODES - 1)) << 24) | s4.w, __float_as_int(w4.w)); bkid[pos] = (unsigned short)bk;
    }
    for (int i = nvec + t; i < cnt; i += 256) {
        int d = dst[beg + i], sv = src[beg + i];
        int bk = d >> BSHIFT;
        int pos = atomicAdd(&hist[bk], 1);
        stage[pos] = make_int2(((d & (BNODES - 1)) << 24) | sv, __float_as_int(w[beg + i]));
        bkid[pos] = (unsigned short)bk;
    }
    __syncthreads();
    // write-out: linear over stage -> coalesced runs at reserved global offsets
    for (int i = t; i < cnt; i += 256) {
        int bk = bkid[i];
        edata[basev[bk] + (i - pfx[bk])] = stage[i];
    }
}

// per-bucket counting sort (LDS staging) + rowptr emission + weighted-degree -> dinv
__global__ __launch_bounds__(256) void k_bsort(int2* __restrict__ edata,
                                               const int* __restrict__ bptr,
                                               int* __restrict__ rowptr,
                                               float* __restrict__ dinv, int N) {
    __shared__ int2 stage[SORTCAP];
    __shared__ int hist[BNODES];
    __shared__ int cur[BNODES];
    __shared__ int ts[BNODES];
    __shared__ float wsum[BNODES];
    int t = threadIdx.x;
    int b = blockIdx.x;
    int beg = bptr[b], end = bptr[b + 1];
    int cnt = end - beg;
    if (t < BNODES) { hist[t] = 0; wsum[t] = 0.f; }
    __syncthreads();
    for (int i = t; i < cnt; i += 256) {
        int2 r = edata[beg + i];
        stage[i] = r;
        int doff = ((unsigned)r.x) >> 24;
        atomicAdd(&hist[doff], 1);
        atomicAdd(&wsum[doff], __int_as_float(r.y));
    }
    __syncthreads();
    if (t < BNODES) ts[t] = hist[t];
    __syncthreads();
    for (int off = 1; off < BNODES; off <<= 1) {
        int v = (t < BNODES && t >= off) ? ts[t - off] : 0;
        __syncthreads();
        if (t < BNODES) ts[t] += v;
        __syncthreads();
    }
    if (t < BNODES) {
        int excl = ts[t] - hist[t];
        cur[t] = excl;
        int n = b * BNODES + t;
        if (n < N) {
            rowptr[n] = beg + excl;
            dinv[n] = rsqrtf(1.0f + wsum[t]);   // self-loop weight 1 folded in
        }
    }
    __syncthreads();
    for (int i = t; i < cnt; i += 256) {
        int2 r = stage[i];
        int pos = atomicAdd(&cur[((unsigned)r.x) >> 24], 1);
        edata[beg + pos] = r;   // random within 32KB window: L2-resident
    }
}

// dense transform 1: hs = dinv .* (x @ W1), fp16 output, 16 nodes per block
__global__ __launch_bounds__(256) void k_gemm1(const float* __restrict__ x,
                                               const float* __restrict__ W1,
                                               const float* __restrict__ dinv,
                                               __half* __restrict__ hs) {
    __shared__ float xs[16 * 132];
    __shared__ float ws[NFEAT * HID];
    int t = threadIdx.x;
    for (int i = t; i < NFEAT * HID; i += 256) ws[i] = W1[i];
    const float* xblk = x + (size_t)blockIdx.x * 16 * NFEAT;
    #pragma unroll
    for (int rep = 0; rep < 2; rep++) {
        int i4 = (rep * 256 + t) * 4;
        int row = i4 >> 7, col = i4 & 127;
        float4 v = *reinterpret_cast<const float4*>(xblk + i4);
        *reinterpret_cast<float4*>(&xs[row * 132 + col]) = v;
    }
    __syncthreads();
    int r = t >> 4, j = t & 15;
    int n = blockIdx.x * 16 + r;
    float acc = 0.f;
    #pragma unroll
    for (int k = 0; k < NFEAT; k++) acc += xs[r * 132 + k] * ws[k * HID + j];
    hs[(size_t)n * HID + j] = __float2half(acc * dinv[n]);
}

// per-node register-gather SpMM on dinv-prescaled fp16 features:
//   acc[j] = sum_e w_e * hs[src_e][j];  pre = dv*(acc + hs[n][j]) + b[j]
// 8 nodes/block; per node: 32 lanes = 4 edge-slots x 8 j-pair lanes (half2).
// Hot loop hand-unrolled 4x: batched independent rec loads, then batched gathers.
// LAYER 1: hout = dinv .* (relu(pre) @ W2) (fp16)   LAYER 2: pooled = segment-max relu(pre)
template <int LAYER>
__global__ __launch_bounds__(256) void k_spmm(const __half* __restrict__ hin,
                                              const int2* __restrict__ edata,
                                              const int* __restrict__ rowptr,
                                              const float* __restrict__ dinv,
                                              const float* __restrict__ bias,
                                              const float* __restrict__ W2,
                                              __half* __restrict__ hout,
                                              const int* __restrict__ batch,
                                              unsigned* __restrict__ pooled,
                                              int N) {
    __shared__ float w2s[256];
    __shared__ float act[8][18];
    __shared__ unsigned pool[NGRAPH * HID];
    int t = threadIdx.x;
    if (LAYER == 1) w2s[t] = W2[t];
    if (LAYER == 2) {
        for (int i = t; i < NGRAPH * HID; i += 256) pool[i] = 0u;
        __syncthreads();
    }
    const __half2* hp = reinterpret_cast<const __half2*>(hin);
    int r = t >> 5;                 // node slot
    int sub = (t >> 3) & 3;         // edge slot
    int l8 = t & 7;                 // j-pair index
    int j0 = l8 * 2;
    int n = blockIdx.x * 8 + r;
    float a0 = 0.f, a1 = 0.f;
    if (n < N) {
        int beg = rowptr[n], end = rowptr[n + 1];
        int p = beg + sub;
        // 4x unroll: 4 independent rec loads, then 4 independent gathers
        for (; p + 12 < end; p += 16) {
            int2 r0 = edata[p];
            int2 r1 = edata[p + 4];
            int2 r2 = edata[p + 8];
            int2 r3 = edata[p + 12];
            __half2 q0 = hp[(size_t)(r0.x & 0xFFFFFF) * 8 + l8];
            __half2 q1 = hp[(size_t)(r1.x & 0xFFFFFF) * 8 + l8];
            __half2 q2 = hp[(size_t)(r2.x & 0xFFFFFF) * 8 + l8];
            __half2 q3 = hp[(size_t)(r3.x & 0xFFFFFF) * 8 + l8];
            float2 f0 = __half22float2(q0);
            float2 f1 = __half22float2(q1);
            float2 f2 = __half22float2(q2);
            float2 f3 = __half22float2(q3);
            float w0 = __int_as_float(r0.y), w1 = __int_as_float(r1.y);
            float w2 = __int_as_float(r2.y), w3 = __int_as_float(r3.y);
            a0 += w0 * f0.x; a1 += w0 * f0.y;
            a0 += w1 * f1.x; a1 += w1 * f1.y;
            a0 += w2 * f2.x; a1 += w2 * f2.y;
            a0 += w3 * f3.x; a1 += w3 * f3.y;
        }
        for (; p < end; p += 4) {
            int2 rc = edata[p];
            __half2 q = hp[(size_t)(rc.x & 0xFFFFFF) * 8 + l8];
            float2 f = __half22float2(q);
            float wv = __int_as_float(rc.y);
            a0 += wv * f.x; a1 += wv * f.y;
        }
    }
    a0 += __shfl_xor(a0, 8, 32);  a1 += __shfl_xor(a1, 8, 32);
    a0 += __shfl_xor(a0, 16, 32); a1 += __shfl_xor(a1, 16, 32);
    float v0 = 0.f, v1 = 0.f;
    if (n < N) {
        float dv = dinv[n];
        float2 sf = __half22float2(hp[(size_t)n * 8 + l8]);
        v0 = dv * (a0 + sf.x) + bias[j0];
        v1 = dv * (a1 + sf.y) + bias[j0 + 1];
        v0 = v0 > 0.f ? v0 : 0.f;
        v1 = v1 > 0.f ? v1 : 0.f;
    }
    if (LAYER == 1) {
        if (sub == 0 && n < N) { act[r][j0] = v0; act[r][j0 + 1] = v1; }
        __syncthreads();
        int j = t & 15, hf = (t >> 4) & 1;
        if (hf == 0 && n < N) {
            float o = 0.f;
            #pragma unroll
            for (int k = 0; k < HID; ++k) o += act[r][k] * w2s[k * 16 + j];
            hout[(size_t)n * HID + j] = __float2half(o * dinv[n]);
        }
    } else {
        if (sub == 0 && n < N) {
            int g = batch[n];
            atomicMax(&pool[g * HID + j0], __float_as_uint(v0));
            atomicMax(&pool[g * HID + j0 + 1], __float_as_uint(v1));
        }
        __syncthreads();
        for (int i = t; i < NGRAPH * HID; i += 256) {
            unsigned u = pool[i];
            if (u) atomicMax(&pooled[i], u);
        }
    }
}

__global__ __launch_bounds__(256) void k_final(const unsigned* __restrict__ pooled,
                                               const float* __restrict__ Wl,
                                               const float* __restrict__ bl,
                                               float* __restrict__ out) {
    int gid = blockIdx.x * 256 + threadIdx.x;
    if (gid < NGRAPH * NACT) {
        int g = gid / NACT, a = gid - g * NACT;
        float acc = bl[a];
        #pragma unroll
        for (int k = 0; k < HID; k++)
            acc += __uint_as_float(pooled[g * HID + k]) * Wl[k * NACT + a];
        out[gid] = acc;
    }
}

extern "C" void kernel_launch(void* const* d_in, const int* in_sizes, int n_in,
                              void* d_out, int out_size, void* d_ws, size_t ws_size,
                              hipStream_t stream) {
    const float* x     = (const float*)d_in[0];
    const int*   ei    = (const int*)d_in[1];
    const float* ew    = (const float*)d_in[2];
    const int*   batch = (const int*)d_in[3];
    const float* W1    = (const float*)d_in[4];
    const float* b1    = (const float*)d_in[5];
    const float* W2    = (const float*)d_in[6];
    const float* b2    = (const float*)d_in[7];
    const float* Wl    = (const float*)d_in[8];
    const float* bl    = (const float*)d_in[9];
    float* out = (float*)d_out;

    int N = in_sizes[0] / NFEAT;
    int E = in_sizes[1] / 2;
    const int* srcIdx = ei;
    const int* dstIdx = ei + E;
    int nbuck = (N + BNODES - 1) >> BSHIFT;

    // workspace
    int2*   edata  = (int2*)d_ws;                       // [E]
    float*  dinv   = (float*)(edata + E);               // [N]
    __half* hs     = (__half*)(dinv + N);               // [N*HID] fp16, dinv-prescaled
    __half* hs2    = hs + (size_t)N * HID;              // [N*HID] fp16, dinv-prescaled
    int*    rowptr = (int*)(hs2 + (size_t)N * HID);     // [N+1]
    int*    bcnt   = rowptr + N + 1;                    // [MAXBUCK]
    int*    bptr   = bcnt + MAXBUCK;                    // [MAXBUCK+1]
    int*    cursor = bptr + MAXBUCK + 1;                // [MAXBUCK]
    unsigned* pooled = (unsigned*)(cursor + MAXBUCK);   // [NGRAPH*HID]

    int nbC = (E + CHUNK - 1) / CHUNK;

    hipMemsetAsync(bcnt, 0, MAXBUCK * sizeof(int), stream);
    hipMemsetAsync(pooled, 0, NGRAPH * HID * sizeof(unsigned), stream);

    k_hist    <<<nbC, 256, 0, stream>>>(bcnt, dstIdx, E, nbuck);
    k_scan    <<<1, 1024, 0, stream>>>(bcnt, bptr, cursor, rowptr, nbuck, E, N);
    k_bscatter<<<nbC, 256, 0, stream>>>(edata, cursor, srcIdx, dstIdx, ew, E, nbuck);
    k_bsort   <<<nbuck, 256, 0, stream>>>(edata, bptr, rowptr, dinv, N);

    k_gemm1   <<<N / 16, 256, 0, stream>>>(x, W1, dinv, hs);
    k_spmm<1> <<<(N + 7) / 8, 256, 0, stream>>>(hs, edata, rowptr, dinv, b1, W2, hs2, batch, pooled, N);
    k_spmm<2> <<<(N + 7) / 8, 256, 0, stream>>>(hs2, edata, rowptr, dinv, b2, nullptr, nullptr, batch, pooled, N);
    k_final   <<<(NGRAPH * NACT + 255) / 256, 256, 0, stream>>>(pooled, Wl, bl, out);
}